// Round 3
// baseline (136.348 us; speedup 1.0000x reference)
//
#include <hip/hip_runtime.h>

// RBFNN fused, round 3: 4-deep staging pipeline, barrier per stage-PAIR.
// out[B,K] = exp(-gamma * dist(x, centers)) @ W^T + b
// B=16384, F=512, C=1024, K=100.
//
// vs round 2: the per-stage __syncthreads drained vmcnt(0) ~350-600 cyc after
// issue -> every barrier ate the uncovered tail of a ~900-cyc cold fetch
// (~70k stall cyc/CU of the 127k total). Now: 4 x 16KB slab buffers, loads
// for pair j+1 issued right after pair-j's entry barrier -> ~2 stages
// (660-1000 cyc) of cover before the draining barrier. B slabs k=32 (16KB),
// W slabs k=64 (16KB, XOR-swizzled kcell^(row&7) to kill a true 2x read
// conflict). Slab n -> buffer n%4. Prologue pre-issues slabs 0..3 under the
// ~12k-cycle x-staging shadow. One phi buffer (64x132), E1 in its own
// barrier-delimited slot. All MFMA frag reads verified at the 8-access/bank
// LDS floor. 1 block/CU (grid 256), LDS ~148 KB.

#define NB 16384
#define NF 512
#define NC 1024
#define NK 100

#define A_PITCH 516   // bf16 elems; 1032 B row; frag reads at bank floor
#define P_PITCH 132   // phi pitch; 264 B row; bank floor

#define WS_NEED (NC * NF * 2 + NC * 4 + 128 * NC * 2)  // cb + csq + wb

typedef __attribute__((ext_vector_type(8))) short short8;
typedef __attribute__((ext_vector_type(4))) short short4v;
typedef __attribute__((ext_vector_type(4))) float f4;
typedef unsigned short ushort;

__device__ __forceinline__ short bf16t(float f) {
  return (short)(__float_as_uint(f) >> 16);
}

__device__ __forceinline__ void async_cp16(const void* g, void* l) {
  __builtin_amdgcn_global_load_lds(
      (const __attribute__((address_space(1))) void*)g,
      (__attribute__((address_space(3))) void*)l, 16, 0, 0);
}

// ---------------- prepass kernels ----------------

__global__ __launch_bounds__(256) void prep_centers(
    const float* __restrict__ ctr, ushort* __restrict__ cbp,
    float* __restrict__ csq) {
  const int row = blockIdx.x * 4 + (threadIdx.x >> 6);
  const int lane = threadIdx.x & 63;
  const f4* src = (const f4*)(ctr + (size_t)row * NF + lane * 8);
  f4 v0 = src[0], v1 = src[1];
  float xp = v0.x * v0.x + v0.y * v0.y + v0.z * v0.z + v0.w * v0.w +
             v1.x * v1.x + v1.y * v1.y + v1.z * v1.z + v1.w * v1.w;
  short4v h0, h1;
  h0.x = bf16t(v0.x); h0.y = bf16t(v0.y); h0.z = bf16t(v0.z); h0.w = bf16t(v0.w);
  h1.x = bf16t(v1.x); h1.y = bf16t(v1.y); h1.z = bf16t(v1.z); h1.w = bf16t(v1.w);
  short* dst = (short*)(cbp + (size_t)row * NF + lane * 8);
  *(short4v*)dst = h0;
  *(short4v*)(dst + 4) = h1;
#pragma unroll
  for (int off = 32; off > 0; off >>= 1) xp += __shfl_down(xp, off, 64);
  if (lane == 0) csq[row] = xp;
}

__global__ __launch_bounds__(256) void prep_w(const float* __restrict__ W,
                                              ushort* __restrict__ wb) {
  const int row = blockIdx.x;
  const int col = threadIdx.x * 4;
  short4v h = {0, 0, 0, 0};
  if (row < NK) {
    f4 v = *(const f4*)(W + (size_t)row * NC + col);
    h.x = bf16t(v.x); h.y = bf16t(v.y); h.z = bf16t(v.z); h.w = bf16t(v.w);
  }
  *(short4v*)((short*)wb + (size_t)row * NC + col) = h;
}

// ---------------- main kernel ----------------

__global__ __launch_bounds__(256, 1)
void rbf_main(const float* __restrict__ x, const ushort* __restrict__ cbp,
              const float* __restrict__ csqp, const ushort* __restrict__ wbp,
              const float* __restrict__ bvec, const float* __restrict__ gamma_p,
              float* __restrict__ out) {
  __shared__ alignas(16) short a_lds[64 * A_PITCH];    // 66048 B
  __shared__ alignas(16) char bufs[4][16384];          // 65536 B
  __shared__ alignas(16) short phi_lds[64 * P_PITCH];  // 16896 B
  __shared__ float xsq[64];

  const int tid = threadIdx.x;
  const int lane = tid & 63;
  const int wv = tid >> 6;
  const int lm = lane & 15;
  const int lg = lane >> 4;
  const int m0 = blockIdx.x * 64;
  const float gma = gamma_p[0];

  // staging geometry: slab cell idx = ir*256 + tid, 16B cells.
  // B slab [row 0..255][kcell 0..3]: row = ir*64 + (tid>>2), kcell = tid&3.
  // W slab [kout 0..127][kcellL 0..7]: kout = ir*32+(tid>>3), kcellL = tid&7,
  //   global kcell = kcellL ^ (kout&7).
  char* const my_dst = (char*)nullptr;  // (dest built per call: wave-uniform)

  auto issue_B = [&](int c0, int kb, int pb) {
    char* l = bufs[pb] + wv * 1024;
    const ushort* g = cbp + (size_t)(c0 + (tid >> 2)) * NF + kb * 32 + (tid & 3) * 8;
#pragma unroll
    for (int ir = 0; ir < 4; ++ir)
      async_cp16(g + (size_t)ir * 64 * NF, l + ir * 4096);
  };
  auto issue_W = [&](int c0, int u, int pb) {
    char* l = bufs[pb] + wv * 1024;
    const int kg = (tid & 7) ^ ((tid >> 3) & 7);
    const ushort* g = wbp + (size_t)(tid >> 3) * NC + c0 + u * 64 + kg * 8;
#pragma unroll
    for (int ir = 0; ir < 4; ++ir)
      async_cp16(g + (size_t)ir * 32 * NC, l + ir * 4096);
  };

  int ni_c = 0, ni_r = 4;  // next slab to issue (slabs 0..3 pre-issued)
  auto issue_next_pair = [&]() {
#pragma unroll
    for (int k = 0; k < 2; ++k) {
      if (ni_c < 4) {
        const int pb = ni_r & 3;
        if (ni_r < 16) issue_B(ni_c * 256, ni_r, pb);
        else           issue_W(ni_c * 256, ni_r - 16, pb);
        if (++ni_r == 20) { ni_r = 0; ++ni_c; }
      }
    }
  };

  // ---- prologue: pre-issue slabs 0..3, stage x tile + xsq ----
  issue_B(0, 0, 0);
  issue_B(0, 1, 1);
  issue_B(0, 2, 2);
  issue_B(0, 3, 3);
  {
    const int row = tid >> 2;
    const int seg = tid & 3;
    const f4* xr = (const f4*)(x + (size_t)(m0 + row) * NF + seg * 128);
    short* ar = a_lds + row * A_PITCH + seg * 128;
    float xp = 0.f;
#pragma unroll
    for (int i = 0; i < 32; ++i) {
      f4 v = xr[i];
      xp += v.x * v.x + v.y * v.y + v.z * v.z + v.w * v.w;
      short4v h;
      h.x = bf16t(v.x); h.y = bf16t(v.y); h.z = bf16t(v.z); h.w = bf16t(v.w);
      *(short4v*)(ar + i * 4) = h;
    }
    ((float*)phi_lds)[tid] = xp;  // scratch partials
  }
  __syncthreads();  // drains slabs 0..3 + x tile (huge cover: full prologue)
  if (tid < 64) {
    const float* pp = (const float*)phi_lds;
    xsq[tid] = pp[4 * tid] + pp[4 * tid + 1] + pp[4 * tid + 2] + pp[4 * tid + 3];
  }  // first read at E0, many barriers later

  const f4 fzero = {0.f, 0.f, 0.f, 0.f};
  f4 acc2[4][2];
#pragma unroll
  for (int i = 0; i < 4; ++i)
#pragma unroll
    for (int n = 0; n < 2; ++n) acc2[i][n] = fzero;

  auto compute1 = [&](const char* buf, int kb, f4 (*acc1)[4]) {
    short8 av[4], bv[4];
#pragma unroll
    for (int i = 0; i < 4; ++i)
      av[i] = *(const short8*)(a_lds + (16 * i + lm) * A_PITCH + kb * 32 + lg * 8);
#pragma unroll
    for (int t = 0; t < 4; ++t)
      bv[t] = *(const short8*)(buf + (16 * (wv + 4 * t) + lm) * 64 + lg * 16);
#pragma unroll
    for (int i = 0; i < 4; ++i)
#pragma unroll
      for (int t = 0; t < 4; ++t)
        acc1[i][t] = __builtin_amdgcn_mfma_f32_16x16x32_bf16(
            av[i], bv[t], acc1[i][t], 0, 0, 0);
  };

  auto compute2 = [&](const char* buf, int u) {
    const int ul = (u & 1) * 64;
#pragma unroll
    for (int s = 0; s < 2; ++s) {
      short8 pv[4], wv8[2];
#pragma unroll
      for (int i = 0; i < 4; ++i)
        pv[i] = *(const short8*)(phi_lds + (16 * i + lm) * P_PITCH + ul +
                                 s * 32 + lg * 8);
#pragma unroll
      for (int n = 0; n < 2; ++n)
        wv8[n] = *(const short8*)(buf + (16 * (2 * wv + n) + lm) * 128 +
                                  (((4 * s + lg) ^ (lm & 7)) << 4));
#pragma unroll
      for (int i = 0; i < 4; ++i)
#pragma unroll
        for (int n = 0; n < 2; ++n)
          acc2[i][n] = __builtin_amdgcn_mfma_f32_16x16x32_bf16(
              pv[i], wv8[n], acc2[i][n], 0, 0, 0);
    }
  };

  for (int c = 0; c < 4; ++c) {
    const int c0 = c * 256;
    float csr_c[4];
#pragma unroll
    for (int t = 0; t < 4; ++t)
      csr_c[t] = csqp[c0 + 16 * (wv + 4 * t) + lm];

    f4 acc1[4][4];
#pragma unroll
    for (int i = 0; i < 4; ++i)
#pragma unroll
      for (int t = 0; t < 4; ++t) acc1[i][t] = fzero;

    auto epilogue_half = [&](int h) {
#pragma unroll
      for (int t2 = 0; t2 < 2; ++t2) {
        const int t = 2 * h + t2;
        const float cs = csr_c[t];
        const int colh = 16 * (wv + 4 * t2) + lm;
#pragma unroll
        for (int i = 0; i < 4; ++i) {
#pragma unroll
          for (int r = 0; r < 4; ++r) {
            const int rowL = 16 * i + 4 * lg + r;
            float d2 = xsq[rowL] + cs - 2.0f * acc1[i][t][r];
            d2 = fmaxf(d2, 0.f);
            const float ph = __expf(-gma * __builtin_amdgcn_sqrtf(d2));
            phi_lds[rowL * P_PITCH + colh] = bf16t(ph);
          }
        }
      }
    };

    // ---- GEMM1: 8 pairs of k=32 B stages ----
#pragma unroll
    for (int q = 0; q < 8; ++q) {
      if (c | q) {
        __syncthreads();     // drains the pair issued one pair ago
        issue_next_pair();   // into buffers freed by the pair before that
      }
      compute1(bufs[(2 * q) & 3], 2 * q, acc1);
      compute1(bufs[(2 * q + 1) & 3], 2 * q + 1, acc1);
    }
    epilogue_half(0);        // before W-pair0 barrier -> visible to W0/W1

    // ---- W pair 0 (slabs 16,17 -> bufs 0,1) ----
    __syncthreads();
    issue_next_pair();       // W2,W3
    compute2(bufs[0], 0);
    compute2(bufs[1], 1);

    __syncthreads();         // all waves done reading phi half-0 content
    epilogue_half(1);

    // ---- W pair 1 (slabs 18,19 -> bufs 2,3) ----
    __syncthreads();         // publishes E1; drains W2,W3 (already landed)
    issue_next_pair();       // next chunk's B0,B1 (no-op after chunk 3)
    compute2(bufs[2], 2);
    compute2(bufs[3], 3);
  }

  // ---- out = acc2 + b, kout = 32wv + 16n + lm < 100 ----
#pragma unroll
  for (int i = 0; i < 4; ++i) {
#pragma unroll
    for (int n = 0; n < 2; ++n) {
      const int kout = 32 * wv + 16 * n + lm;
      if (kout < NK) {
        const float bb = bvec[kout];
#pragma unroll
        for (int r = 0; r < 4; ++r) {
          const int row = m0 + 16 * i + 4 * lg + r;
          out[(size_t)row * NK + kout] = acc2[i][n][r] + bb;
        }
      }
    }
  }
  (void)my_dst;
}

// ---------------- fallback (round-1 kernel, used if ws too small) ----------------

#define A_PITCH1 520
#define BW_PITCH1 72
#define PHI_PITCH1 264

__global__ __launch_bounds__(256, 1)
void rbf_fused_v1(const float* __restrict__ x, const float* __restrict__ ctr,
                  const float* __restrict__ gamma_p, const float* __restrict__ W,
                  const float* __restrict__ bvec, float* __restrict__ out) {
  __shared__ alignas(16) short a_lds[64 * A_PITCH1];
  __shared__ alignas(16) short bw_lds[256 * BW_PITCH1];
  __shared__ alignas(16) short phi_lds[64 * PHI_PITCH1];
  __shared__ float xsq[64];
  __shared__ float csq[256];

  const int tid = threadIdx.x;
  const int lane = tid & 63;
  const int wv = tid >> 6;
  const int lm = lane & 15;
  const int lg = lane >> 4;
  const int m0 = blockIdx.x * 64;
  const float gma = gamma_p[0];

  {
    const int row = tid >> 2;
    const int seg = tid & 3;
    const float* xr = x + (size_t)(m0 + row) * NF + seg * 128;
    short* ar = a_lds + row * A_PITCH1 + seg * 128;
    float xp = 0.f;
#pragma unroll
    for (int i = 0; i < 32; ++i) {
      f4 v = ((const f4*)xr)[i];
      xp += v.x * v.x + v.y * v.y + v.z * v.z + v.w * v.w;
      short4v h;
      h.x = bf16t(v.x); h.y = bf16t(v.y); h.z = bf16t(v.z); h.w = bf16t(v.w);
      *(short4v*)(ar + i * 4) = h;
    }
    ((float*)phi_lds)[tid] = xp;
  }
  __syncthreads();
  if (tid < 64) {
    const float* pp = (const float*)phi_lds;
    xsq[tid] = pp[tid * 4] + pp[tid * 4 + 1] + pp[tid * 4 + 2] + pp[tid * 4 + 3];
  }

  const f4 fzero = {0.f, 0.f, 0.f, 0.f};
  f4 acc2[4][2];
#pragma unroll
  for (int i = 0; i < 4; ++i)
#pragma unroll
    for (int n = 0; n < 2; ++n) acc2[i][n] = fzero;

  const short* a_base = a_lds + lm * A_PITCH1 + lg * 8;
  const short* b_base = bw_lds + (64 * wv + lm) * BW_PITCH1 + lg * 8;
  const short* w_base = bw_lds + lm * BW_PITCH1 + lg * 8;
  const short* p_base = phi_lds + lm * PHI_PITCH1 + lg * 8;

  for (int chunk = 0; chunk < 4; ++chunk) {
    const int c0 = chunk * 256;
    f4 acc1[4][4];
#pragma unroll
    for (int i = 0; i < 4; ++i)
#pragma unroll
      for (int t = 0; t < 4; ++t) acc1[i][t] = fzero;
    float cpriv = 0.f;

    for (int kb = 0; kb < 8; ++kb) {
      __syncthreads();
      {
        const float* cr = ctr + (size_t)(c0 + tid) * NF + kb * 64;
        short* br = bw_lds + tid * BW_PITCH1;
#pragma unroll
        for (int i = 0; i < 16; ++i) {
          f4 v = ((const f4*)cr)[i];
          cpriv += v.x * v.x + v.y * v.y + v.z * v.z + v.w * v.w;
          short4v h;
          h.x = bf16t(v.x); h.y = bf16t(v.y); h.z = bf16t(v.z); h.w = bf16t(v.w);
          *(short4v*)(br + i * 4) = h;
        }
      }
      __syncthreads();
#pragma unroll
      for (int s = 0; s < 2; ++s) {
        short8 av[4], bv8[4];
#pragma unroll
        for (int i = 0; i < 4; ++i)
          av[i] = *(const short8*)(a_base + 16 * i * A_PITCH1 + 64 * kb + 32 * s);
#pragma unroll
        for (int t = 0; t < 4; ++t)
          bv8[t] = *(const short8*)(b_base + 16 * t * BW_PITCH1 + 32 * s);
#pragma unroll
        for (int i = 0; i < 4; ++i)
#pragma unroll
          for (int t = 0; t < 4; ++t)
            acc1[i][t] = __builtin_amdgcn_mfma_f32_16x16x32_bf16(
                av[i], bv8[t], acc1[i][t], 0, 0, 0);
      }
    }

    csq[tid] = cpriv;
    __syncthreads();

#pragma unroll
    for (int i = 0; i < 4; ++i) {
#pragma unroll
      for (int t = 0; t < 4; ++t) {
        const int colL = 64 * wv + 16 * t + lm;
        const float cs = csq[colL];
#pragma unroll
        for (int r = 0; r < 4; ++r) {
          const int rowL = 16 * i + 4 * lg + r;
          float d2 = xsq[rowL] + cs - 2.0f * acc1[i][t][r];
          d2 = fmaxf(d2, 0.f);
          const float ph = __expf(-gma * __fsqrt_rn(d2));
          phi_lds[rowL * PHI_PITCH1 + colL] = bf16t(ph);
        }
      }
    }

    for (int u = 0; u < 4; ++u) {
      __syncthreads();
      {
        const int row = tid >> 1;
        const int half = tid & 1;
        short* wr = bw_lds + row * BW_PITCH1 + half * 32;
        if (row < NK) {
          const float* ws = W + (size_t)row * NC + c0 + u * 64 + half * 32;
#pragma unroll
          for (int i = 0; i < 8; ++i) {
            f4 v = ((const f4*)ws)[i];
            short4v h;
            h.x = bf16t(v.x); h.y = bf16t(v.y); h.z = bf16t(v.z); h.w = bf16t(v.w);
            *(short4v*)(wr + i * 4) = h;
          }
        } else {
          const short4v zz = {0, 0, 0, 0};
#pragma unroll
          for (int i = 0; i < 8; ++i) *(short4v*)(wr + i * 4) = zz;
        }
      }
      __syncthreads();
#pragma unroll
      for (int s = 0; s < 2; ++s) {
        short8 pv[4], wv8[2];
#pragma unroll
        for (int i = 0; i < 4; ++i)
          pv[i] = *(const short8*)(p_base + 16 * i * PHI_PITCH1 + 64 * u + 32 * s);
#pragma unroll
        for (int n = 0; n < 2; ++n)
          wv8[n] = *(const short8*)(w_base + 16 * (2 * wv + n) * BW_PITCH1 + 32 * s);
#pragma unroll
        for (int i = 0; i < 4; ++i)
#pragma unroll
          for (int n = 0; n < 2; ++n)
            acc2[i][n] = __builtin_amdgcn_mfma_f32_16x16x32_bf16(
                pv[i], wv8[n], acc2[i][n], 0, 0, 0);
      }
    }
  }

#pragma unroll
  for (int i = 0; i < 4; ++i) {
#pragma unroll
    for (int n = 0; n < 2; ++n) {
      const int kout = 32 * wv + 16 * n + lm;
      if (kout < NK) {
        const float bb = bvec[kout];
#pragma unroll
        for (int r = 0; r < 4; ++r) {
          const int row = m0 + 16 * i + 4 * lg + r;
          out[(size_t)row * NK + kout] = acc2[i][n][r] + bb;
        }
      }
    }
  }
}

extern "C" void kernel_launch(void* const* d_in, const int* in_sizes, int n_in,
                              void* d_out, int out_size, void* d_ws, size_t ws_size,
                              hipStream_t stream) {
  (void)in_sizes; (void)n_in; (void)out_size;
  const float* x       = (const float*)d_in[0];
  const float* centers = (const float*)d_in[1];
  const float* gamma   = (const float*)d_in[2];
  const float* W       = (const float*)d_in[3];
  const float* b       = (const float*)d_in[4];
  float* out = (float*)d_out;

  if (ws_size >= (size_t)WS_NEED) {
    char* wsb = (char*)d_ws;
    ushort* cbp = (ushort*)wsb;                          // 1024*512 bf16
    float* csqp = (float*)(wsb + NC * NF * 2);           // 1024 f32
    ushort* wbp = (ushort*)(wsb + NC * NF * 2 + NC * 4); // 128*1024 bf16
    prep_centers<<<dim3(NC / 4), dim3(256), 0, stream>>>(centers, cbp, csqp);
    prep_w<<<dim3(128), dim3(256), 0, stream>>>(W, wbp);
    rbf_main<<<dim3(NB / 64), dim3(256), 0, stream>>>(x, cbp, csqp, wbp, b,
                                                      gamma, out);
  } else {
    rbf_fused_v1<<<dim3(NB / 64), dim3(256), 0, stream>>>(x, centers, gamma, W,
                                                          b, out);
  }
}

// Round 4
// 122.870 us; speedup vs baseline: 1.1097x; 1.1097x over previous
//
#include <hip/hip_runtime.h>

// RBFNN fused, round 4: round-2 pipeline structure + 8 waves/block (512 thr).
// out[B,K] = exp(-gamma * dist(x, centers)) @ W^T + b
// B=16384, F=512, C=1024, K=100.
//
// R3 post-mortem: __syncthreads drains vmcnt(0) for ALL outstanding loads,
// so >1-interval prefetch depth is structurally useless (reproduces
// m131-m141). R3's state machine also added ~30% VALU. Reverted to R2's
// straight-line 2-buffer pipeline. The real limiter at 53us was 1 wave/SIMD
// (Occupancy 10%): MFMA busy 7.6us + VALU 7.5us of 53us elapsed -> ~70%
// exposed latency with no co-resident wave to cover it (m114 mechanism).
// Fix: 512 threads = 8 waves = 2 waves/SIMD, same LDS (~148KB, 1 block/CU).
// GEMM1 wave tile 32x64 (wave = (h=row half, g=col group), acc1[2][4]);
// GEMM2: wave owns 16 kouts (acc2[4]). All LDS frag layouts at the verified
// 8-access/bank floor; B/W staging XOR-swizzled (cell ^ (row&7)) because
// global_load_lds forbids padding.

#define NB 16384
#define NF 512
#define NC 1024
#define NK 100

#define A_PITCH 516   // bf16 elems; frag reads at bank floor
#define P_PITCH 132   // phi half-buffer pitch (128 cols + 4 pad)

#define WS_NEED (NC * NF * 2 + NC * 4 + 128 * NC * 2)  // cb + csq + wb

typedef __attribute__((ext_vector_type(8))) short short8;
typedef __attribute__((ext_vector_type(4))) short short4v;
typedef __attribute__((ext_vector_type(4))) float f4;
typedef unsigned short ushort;

__device__ __forceinline__ short bf16t(float f) {
  return (short)(__float_as_uint(f) >> 16);
}

__device__ __forceinline__ void async_cp16(const void* g, void* l) {
  __builtin_amdgcn_global_load_lds(
      (const __attribute__((address_space(1))) void*)g,
      (__attribute__((address_space(3))) void*)l, 16, 0, 0);
}

// ---------------- prepass kernels ----------------

__global__ __launch_bounds__(256) void prep_centers(
    const float* __restrict__ ctr, ushort* __restrict__ cbp,
    float* __restrict__ csq) {
  const int row = blockIdx.x * 4 + (threadIdx.x >> 6);
  const int lane = threadIdx.x & 63;
  const f4* src = (const f4*)(ctr + (size_t)row * NF + lane * 8);
  f4 v0 = src[0], v1 = src[1];
  float xp = v0.x * v0.x + v0.y * v0.y + v0.z * v0.z + v0.w * v0.w +
             v1.x * v1.x + v1.y * v1.y + v1.z * v1.z + v1.w * v1.w;
  short4v h0, h1;
  h0.x = bf16t(v0.x); h0.y = bf16t(v0.y); h0.z = bf16t(v0.z); h0.w = bf16t(v0.w);
  h1.x = bf16t(v1.x); h1.y = bf16t(v1.y); h1.z = bf16t(v1.z); h1.w = bf16t(v1.w);
  short* dst = (short*)(cbp + (size_t)row * NF + lane * 8);
  *(short4v*)dst = h0;
  *(short4v*)(dst + 4) = h1;
#pragma unroll
  for (int off = 32; off > 0; off >>= 1) xp += __shfl_down(xp, off, 64);
  if (lane == 0) csq[row] = xp;
}

__global__ __launch_bounds__(256) void prep_w(const float* __restrict__ W,
                                              ushort* __restrict__ wb) {
  const int row = blockIdx.x;
  const int col = threadIdx.x * 4;
  short4v h = {0, 0, 0, 0};
  if (row < NK) {
    f4 v = *(const f4*)(W + (size_t)row * NC + col);
    h.x = bf16t(v.x); h.y = bf16t(v.y); h.z = bf16t(v.z); h.w = bf16t(v.w);
  }
  *(short4v*)((short*)wb + (size_t)row * NC + col) = h;
}

// ---------------- main kernel ----------------

__global__ __launch_bounds__(512, 1)
void rbf_main(const float* __restrict__ x, const ushort* __restrict__ cbp,
              const float* __restrict__ csqp, const ushort* __restrict__ wbp,
              const float* __restrict__ bvec, const float* __restrict__ gamma_p,
              float* __restrict__ out) {
  __shared__ alignas(16) short a_lds[64 * A_PITCH];    // 66048 B
  __shared__ alignas(16) char bufs[2][32768];          // 65536 B
  __shared__ alignas(16) short phi_lds[64 * P_PITCH];  // 16896 B
  __shared__ float xsq[64];

  const int tid = threadIdx.x;
  const int lane = tid & 63;
  const int wv = tid >> 6;   // 0..7
  const int h = wv >> 2;     // GEMM1 row half
  const int g = wv & 3;      // GEMM1 col group (interleaved frags g+4t)
  const int lm = lane & 15;
  const int lg = lane >> 4;
  const int m0 = blockIdx.x * 64;
  const float gma = gamma_p[0];

  // staging: 16B cells, idx = ir*512 + tid; row = ir*64 + (tid>>3);
  // LDS cell (tid&7) holds global cell (tid&7)^(row&7); row&7 == (tid>>3)&7.
  const int tr = tid >> 3;
  const int cc8 = (((tid & 7) ^ (tr & 7)) << 3);  // swizzled cell elem offset
  const int wvbase = wv << 10;

  auto issue_B = [&](int c0, int kb, int pb) {
    // slab: 256 center rows x 64 k, 32KB
    const ushort* gp = cbp + (size_t)(c0 + tr) * NF + kb * 64 + cc8;
    char* l = bufs[pb] + wvbase;
#pragma unroll
    for (int ir = 0; ir < 4; ++ir)
      async_cp16(gp + (size_t)ir * 64 * NF, l + ir * 8192);
  };
  auto issue_W = [&](int c0, int u, int pb) {
    // slab: 128 kout rows x 64 c, 16KB (first half of buffer)
    const ushort* gp = wbp + (size_t)tr * NC + c0 + u * 64 + cc8;
    char* l = bufs[pb] + wvbase;
#pragma unroll
    for (int ir = 0; ir < 2; ++ir)
      async_cp16(gp + (size_t)ir * 64 * NC, l + ir * 8192);
  };

  // ---- prologue: issue B0 of chunk 0, stage x tile + xsq ----
  issue_B(0, 0, 0);
  {
    const int row = tid >> 3;   // 0..63
    const int seg = tid & 7;    // 8 threads/row, 64 floats each
    const f4* xr = (const f4*)(x + (size_t)(m0 + row) * NF + seg * 64);
    short* ar = a_lds + row * A_PITCH + seg * 64;
    float xp = 0.f;
#pragma unroll
    for (int i = 0; i < 16; ++i) {
      f4 v = xr[i];
      xp += v.x * v.x + v.y * v.y + v.z * v.z + v.w * v.w;
      short4v hh;
      hh.x = bf16t(v.x); hh.y = bf16t(v.y); hh.z = bf16t(v.z); hh.w = bf16t(v.w);
      *(short4v*)(ar + i * 4) = hh;
    }
    ((float*)phi_lds)[tid] = xp;  // scratch partials [row*8+seg]
  }
  __syncthreads();  // drains B0 + x tile (cover: full x staging)
  if (tid < 64) {
    const float* pp = (const float*)phi_lds + 8 * tid;
    xsq[tid] = pp[0] + pp[1] + pp[2] + pp[3] + pp[4] + pp[5] + pp[6] + pp[7];
  }  // first read at E0, many barriers later

  const f4 fzero = {0.f, 0.f, 0.f, 0.f};
  f4 acc2[4];
#pragma unroll
  for (int i = 0; i < 4; ++i) acc2[i] = fzero;

  f4 acc1[2][4];

  auto compute1 = [&](const char* buf, int kb) {
#pragma unroll
    for (int s = 0; s < 2; ++s) {
      short8 av[2], bv[4];
#pragma unroll
      for (int i = 0; i < 2; ++i)
        av[i] = *(const short8*)(a_lds + (32 * h + 16 * i + lm) * A_PITCH +
                                 kb * 64 + s * 32 + lg * 8);
#pragma unroll
      for (int t = 0; t < 4; ++t)
        bv[t] = *(const short8*)(buf + (16 * (g + 4 * t) + lm) * 128 +
                                 (((4 * s + lg) ^ (lm & 7)) << 4));
#pragma unroll
      for (int i = 0; i < 2; ++i)
#pragma unroll
        for (int t = 0; t < 4; ++t)
          acc1[i][t] = __builtin_amdgcn_mfma_f32_16x16x32_bf16(
              av[i], bv[t], acc1[i][t], 0, 0, 0);
    }
  };

  auto compute2 = [&](const char* buf, int u) {
    const int ul = (u & 1) * 64;
#pragma unroll
    for (int s = 0; s < 2; ++s) {
      short8 pv[4], wf;
#pragma unroll
      for (int i = 0; i < 4; ++i)
        pv[i] = *(const short8*)(phi_lds + (16 * i + lm) * P_PITCH + ul +
                                 s * 32 + lg * 8);
      wf = *(const short8*)(buf + (16 * wv + lm) * 128 +
                            (((4 * s + lg) ^ (lm & 7)) << 4));
#pragma unroll
      for (int i = 0; i < 4; ++i)
        acc2[i] = __builtin_amdgcn_mfma_f32_16x16x32_bf16(pv[i], wf, acc2[i],
                                                          0, 0, 0);
    }
  };

  int p = 0;
  for (int c = 0; c < 4; ++c) {
    const int c0 = c * 256;
    float csr[4];
#pragma unroll
    for (int t = 0; t < 4; ++t)
      csr[t] = csqp[c0 + 16 * (g + 4 * t) + lm];

#pragma unroll
    for (int i = 0; i < 2; ++i)
#pragma unroll
      for (int t = 0; t < 4; ++t) acc1[i][t] = fzero;

    // phi half H covers chunk cols 128H..128H+127; wave's frags there are
    // t = 2H, 2H+1 -> col-in-half = 16*(g+4*t2)+lm.
    auto epilogue_half = [&](int hh) {
#pragma unroll
      for (int t2 = 0; t2 < 2; ++t2) {
        const int t = 2 * hh + t2;
        const float cs = csr[t];
        const int colh = 16 * (g + 4 * t2) + lm;
#pragma unroll
        for (int i = 0; i < 2; ++i) {
#pragma unroll
          for (int r = 0; r < 4; ++r) {
            const int rowL = 32 * h + 16 * i + 4 * lg + r;
            float d2 = xsq[rowL] + cs - 2.0f * acc1[i][t][r];
            d2 = fmaxf(d2, 0.f);
            const float ph = __expf(-gma * __builtin_amdgcn_sqrtf(d2));
            phi_lds[rowL * P_PITCH + colh] = bf16t(ph);
          }
        }
      }
    };

    // ---- GEMM1: 8 k=64 B stages, issue next at top, barrier per stage ----
#pragma unroll
    for (int kb = 0; kb < 8; ++kb) {
      if (kb < 7) issue_B(c0, kb + 1, p ^ 1);
      else        issue_W(c0, 0, p ^ 1);
      compute1(bufs[p], kb);
      __syncthreads();
      p ^= 1;
    }

    // ---- E0 | W0 | W1 | E1 | W2 | W3 ----
    issue_W(c0, 1, p ^ 1);
    epilogue_half(0);
    __syncthreads();          // publishes phi half-0; no flip

    compute2(bufs[p], 0);
    __syncthreads();
    p ^= 1;

    issue_W(c0, 2, p ^ 1);
    compute2(bufs[p], 1);
    __syncthreads();          // all waves done reading phi half-0
    p ^= 1;

    issue_W(c0, 3, p ^ 1);
    epilogue_half(1);
    __syncthreads();          // publishes phi half-1; no flip

    compute2(bufs[p], 2);
    __syncthreads();
    p ^= 1;

    if (c < 3) issue_B(c0 + 256, 0, p ^ 1);
    compute2(bufs[p], 3);
    __syncthreads();
    p ^= 1;
  }

  // ---- out = acc2 + b, kout = 16*wv + lm < 100 ----
  const int kout = 16 * wv + lm;
  if (kout < NK) {
    const float bb = bvec[kout];
#pragma unroll
    for (int i = 0; i < 4; ++i) {
#pragma unroll
      for (int r = 0; r < 4; ++r) {
        const int row = m0 + 16 * i + 4 * lg + r;
        out[(size_t)row * NK + kout] = acc2[i][r] + bb;
      }
    }
  }
}

// ---------------- fallback (round-1 kernel, used if ws too small) ----------------

#define A_PITCH1 520
#define BW_PITCH1 72
#define PHI_PITCH1 264

__global__ __launch_bounds__(256, 1)
void rbf_fused_v1(const float* __restrict__ x, const float* __restrict__ ctr,
                  const float* __restrict__ gamma_p, const float* __restrict__ W,
                  const float* __restrict__ bvec, float* __restrict__ out) {
  __shared__ alignas(16) short a_lds[64 * A_PITCH1];
  __shared__ alignas(16) short bw_lds[256 * BW_PITCH1];
  __shared__ alignas(16) short phi_lds[64 * PHI_PITCH1];
  __shared__ float xsq[64];
  __shared__ float csq[256];

  const int tid = threadIdx.x;
  const int lane = tid & 63;
  const int wv = tid >> 6;
  const int lm = lane & 15;
  const int lg = lane >> 4;
  const int m0 = blockIdx.x * 64;
  const float gma = gamma_p[0];

  {
    const int row = tid >> 2;
    const int seg = tid & 3;
    const float* xr = x + (size_t)(m0 + row) * NF + seg * 128;
    short* ar = a_lds + row * A_PITCH1 + seg * 128;
    float xp = 0.f;
#pragma unroll
    for (int i = 0; i < 32; ++i) {
      f4 v = ((const f4*)xr)[i];
      xp += v.x * v.x + v.y * v.y + v.z * v.z + v.w * v.w;
      short4v h;
      h.x = bf16t(v.x); h.y = bf16t(v.y); h.z = bf16t(v.z); h.w = bf16t(v.w);
      *(short4v*)(ar + i * 4) = h;
    }
    ((float*)phi_lds)[tid] = xp;
  }
  __syncthreads();
  if (tid < 64) {
    const float* pp = (const float*)phi_lds;
    xsq[tid] = pp[tid * 4] + pp[tid * 4 + 1] + pp[tid * 4 + 2] + pp[tid * 4 + 3];
  }

  const f4 fzero = {0.f, 0.f, 0.f, 0.f};
  f4 acc2[4][2];
#pragma unroll
  for (int i = 0; i < 4; ++i)
#pragma unroll
    for (int n = 0; n < 2; ++n) acc2[i][n] = fzero;

  const short* a_base = a_lds + lm * A_PITCH1 + lg * 8;
  const short* b_base = bw_lds + (64 * wv + lm) * BW_PITCH1 + lg * 8;
  const short* w_base = bw_lds + lm * BW_PITCH1 + lg * 8;
  const short* p_base = phi_lds + lm * PHI_PITCH1 + lg * 8;

  for (int chunk = 0; chunk < 4; ++chunk) {
    const int c0 = chunk * 256;
    f4 acc1[4][4];
#pragma unroll
    for (int i = 0; i < 4; ++i)
#pragma unroll
      for (int t = 0; t < 4; ++t) acc1[i][t] = fzero;
    float cpriv = 0.f;

    for (int kb = 0; kb < 8; ++kb) {
      __syncthreads();
      {
        const float* cr = ctr + (size_t)(c0 + tid) * NF + kb * 64;
        short* br = bw_lds + tid * BW_PITCH1;
#pragma unroll
        for (int i = 0; i < 16; ++i) {
          f4 v = ((const f4*)cr)[i];
          cpriv += v.x * v.x + v.y * v.y + v.z * v.z + v.w * v.w;
          short4v h;
          h.x = bf16t(v.x); h.y = bf16t(v.y); h.z = bf16t(v.z); h.w = bf16t(v.w);
          *(short4v*)(br + i * 4) = h;
        }
      }
      __syncthreads();
#pragma unroll
      for (int s = 0; s < 2; ++s) {
        short8 av[4], bv8[4];
#pragma unroll
        for (int i = 0; i < 4; ++i)
          av[i] = *(const short8*)(a_base + 16 * i * A_PITCH1 + 64 * kb + 32 * s);
#pragma unroll
        for (int t = 0; t < 4; ++t)
          bv8[t] = *(const short8*)(b_base + 16 * t * BW_PITCH1 + 32 * s);
#pragma unroll
        for (int i = 0; i < 4; ++i)
#pragma unroll
          for (int t = 0; t < 4; ++t)
            acc1[i][t] = __builtin_amdgcn_mfma_f32_16x16x32_bf16(
                av[i], bv8[t], acc1[i][t], 0, 0, 0);
      }
    }

    csq[tid] = cpriv;
    __syncthreads();

#pragma unroll
    for (int i = 0; i < 4; ++i) {
#pragma unroll
      for (int t = 0; t < 4; ++t) {
        const int colL = 64 * wv + 16 * t + lm;
        const float cs = csq[colL];
#pragma unroll
        for (int r = 0; r < 4; ++r) {
          const int rowL = 16 * i + 4 * lg + r;
          float d2 = xsq[rowL] + cs - 2.0f * acc1[i][t][r];
          d2 = fmaxf(d2, 0.f);
          const float ph = __expf(-gma * __fsqrt_rn(d2));
          phi_lds[rowL * PHI_PITCH1 + colL] = bf16t(ph);
        }
      }
    }

    for (int u = 0; u < 4; ++u) {
      __syncthreads();
      {
        const int row = tid >> 1;
        const int half = tid & 1;
        short* wr = bw_lds + row * BW_PITCH1 + half * 32;
        if (row < NK) {
          const float* ws = W + (size_t)row * NC + c0 + u * 64 + half * 32;
#pragma unroll
          for (int i = 0; i < 8; ++i) {
            f4 v = ((const f4*)ws)[i];
            short4v h;
            h.x = bf16t(v.x); h.y = bf16t(v.y); h.z = bf16t(v.z); h.w = bf16t(v.w);
            *(short4v*)(wr + i * 4) = h;
          }
        } else {
          const short4v zz = {0, 0, 0, 0};
#pragma unroll
          for (int i = 0; i < 8; ++i) *(short4v*)(wr + i * 4) = zz;
        }
      }
      __syncthreads();
#pragma unroll
      for (int s = 0; s < 2; ++s) {
        short8 pv[4], wv8[2];
#pragma unroll
        for (int i = 0; i < 4; ++i)
          pv[i] = *(const short8*)(p_base + 16 * i * PHI_PITCH1 + 64 * u + 32 * s);
#pragma unroll
        for (int n = 0; n < 2; ++n)
          wv8[n] = *(const short8*)(w_base + 16 * (2 * wv + n) * BW_PITCH1 + 32 * s);
#pragma unroll
        for (int i = 0; i < 4; ++i)
#pragma unroll
          for (int n = 0; n < 2; ++n)
            acc2[i][n] = __builtin_amdgcn_mfma_f32_16x16x32_bf16(
                pv[i], wv8[n], acc2[i][n], 0, 0, 0);
      }
    }
  }

#pragma unroll
  for (int i = 0; i < 4; ++i) {
#pragma unroll
    for (int n = 0; n < 2; ++n) {
      const int kout = 32 * wv + 16 * n + lm;
      if (kout < NK) {
        const float bb = bvec[kout];
#pragma unroll
        for (int r = 0; r < 4; ++r) {
          const int row = m0 + 16 * i + 4 * lg + r;
          out[(size_t)row * NK + kout] = acc2[i][n][r] + bb;
        }
      }
    }
  }
}

extern "C" void kernel_launch(void* const* d_in, const int* in_sizes, int n_in,
                              void* d_out, int out_size, void* d_ws, size_t ws_size,
                              hipStream_t stream) {
  (void)in_sizes; (void)n_in; (void)out_size;
  const float* x       = (const float*)d_in[0];
  const float* centers = (const float*)d_in[1];
  const float* gamma   = (const float*)d_in[2];
  const float* W       = (const float*)d_in[3];
  const float* b       = (const float*)d_in[4];
  float* out = (float*)d_out;

  if (ws_size >= (size_t)WS_NEED) {
    char* wsb = (char*)d_ws;
    ushort* cbp = (ushort*)wsb;                          // 1024*512 bf16
    float* csqp = (float*)(wsb + NC * NF * 2);           // 1024 f32
    ushort* wbp = (ushort*)(wsb + NC * NF * 2 + NC * 4); // 128*1024 bf16
    prep_centers<<<dim3(NC / 4), dim3(256), 0, stream>>>(centers, cbp, csqp);
    prep_w<<<dim3(128), dim3(256), 0, stream>>>(W, wbp);
    rbf_main<<<dim3(NB / 64), dim3(512), 0, stream>>>(x, cbp, csqp, wbp, b,
                                                      gamma, out);
  } else {
    rbf_fused_v1<<<dim3(NB / 64), dim3(256), 0, stream>>>(x, centers, gamma, W,
                                                          b, out);
  }
}